// Round 3
// baseline (265.719 us; speedup 1.0000x reference)
//
#include <hip/hip_runtime.h>
#include <hip/hip_bf16.h>

#define BB 8
#define NN 2048
#define DD 128

typedef float f32x4_t __attribute__((ext_vector_type(4)));
typedef short s16x8_t __attribute__((ext_vector_type(8)));

__device__ __forceinline__ unsigned short f2bf(float f){
  union { float f; unsigned int u; } v; v.f = f;
  unsigned int u = v.u;
  u += 0x7FFFu + ((u >> 16) & 1u);   // RNE
  return (unsigned short)(u >> 16);
}
__device__ __forceinline__ float bf2f(unsigned short s){
  union { unsigned int u; float f; } v; v.u = ((unsigned int)s) << 16;
  return v.f;
}
__device__ __forceinline__ s16x8_t pack_bf16_8(const float4 lo, const float4 hi){
  union { __hip_bfloat162 p[4]; s16x8_t v; } U;
  U.p[0] = __float22bfloat162_rn(float2{lo.x, lo.y});
  U.p[1] = __float22bfloat162_rn(float2{lo.z, lo.w});
  U.p[2] = __float22bfloat162_rn(float2{hi.x, hi.y});
  U.p[3] = __float22bfloat162_rn(float2{hi.z, hi.w});
  return U.v;
}

// ---------------------------------------------------------------------------
// Phase 1: h[b][m][e] = leaky_relu(sum_d x[b][m][d] * W[e][d]) in bf16,
// plus transposed copy hT[b][e][m].  1D grid of 256, b = bid&7 (XCD-affine).
// ---------------------------------------------------------------------------
__global__ __launch_bounds__(256) void gc_phase1(const float* __restrict__ x,
                                                 const float* __restrict__ W,
                                                 unsigned short* __restrict__ h,
                                                 unsigned short* __restrict__ hT){
  __shared__ float smem[64*132 + 128*128];   // xs[64][132] + WT[128][128]
  float* xs = smem;
  float* WT = smem + 64*132;

  const int t   = threadIdx.x;
  const int bid = blockIdx.x;
  const int b   = bid & 7;
  const int m0  = (bid >> 3) * 64;

  // W transposed into LDS: WT[d][e] = W[e][d]
  {
    const int e = t >> 1, d0 = (t & 1) * 64;
    const float* wr = W + e*DD + d0;
    #pragma unroll
    for (int i = 0; i < 64; i += 4){
      float4 wv = *(const float4*)(wr + i);
      WT[(d0+i+0)*128 + e] = wv.x;
      WT[(d0+i+1)*128 + e] = wv.y;
      WT[(d0+i+2)*128 + e] = wv.z;
      WT[(d0+i+3)*128 + e] = wv.w;
    }
  }
  // x tile (64 x 128) into LDS, padded stride 132
  #pragma unroll
  for (int i = 0; i < 8; i++){
    int s = t + i*256;
    int row = s >> 5, c4 = (s & 31) * 4;
    float4 xv = *(const float4*)(x + ((size_t)(b*NN + m0 + row))*DD + c4);
    *(float4*)(xs + row*132 + c4) = xv;
  }
  __syncthreads();

  const int rg = t >> 4, cg = t & 15;
  const int r0 = rg*4, c0 = cg*8;
  float acc[4][8];
  #pragma unroll
  for (int i=0;i<4;i++)
    #pragma unroll
    for (int j=0;j<8;j++) acc[i][j] = 0.f;

  #pragma unroll 2
  for (int d = 0; d < 128; d += 4){
    float4 xv[4];
    #pragma unroll
    for (int i=0;i<4;i++) xv[i] = *(const float4*)(xs + (r0+i)*132 + d);
    #pragma unroll
    for (int dd=0; dd<4; dd++){
      float4 wa = *(const float4*)(WT + (d+dd)*128 + c0);
      float4 wb = *(const float4*)(WT + (d+dd)*128 + c0 + 4);
      #pragma unroll
      for (int i=0;i<4;i++){
        float xq = (dd==0)?xv[i].x:(dd==1)?xv[i].y:(dd==2)?xv[i].z:xv[i].w;
        acc[i][0] += xq*wa.x; acc[i][1] += xq*wa.y;
        acc[i][2] += xq*wa.z; acc[i][3] += xq*wa.w;
        acc[i][4] += xq*wb.x; acc[i][5] += xq*wb.y;
        acc[i][6] += xq*wb.z; acc[i][7] += xq*wb.w;
      }
    }
  }

  // leaky relu + bf16, write h (coalesced)
  unsigned short hb[4][8];
  #pragma unroll
  for (int i=0;i<4;i++){
    s16x8_t st;
    #pragma unroll
    for (int j=0;j<8;j++){
      float v = acc[i][j];
      v = v > 0.f ? v : 0.01f*v;
      hb[i][j] = f2bf(v);
      st[j] = (short)hb[i][j];
    }
    *(s16x8_t*)(h + ((size_t)(b*NN + m0 + r0 + i))*DD + c0) = st;
  }

  __syncthreads();
  unsigned short* Tb = (unsigned short*)smem;   // [128][72] bf16 transpose buffer
  #pragma unroll
  for (int i=0;i<4;i++)
    #pragma unroll
    for (int j=0;j<8;j++)
      Tb[(c0+j)*72 + (r0+i)] = hb[i][j];
  __syncthreads();

  {
    const int e = t >> 1, mh = (t & 1) * 32;
    unsigned short* dst = hT + ((size_t)(b*DD + e))*NN + m0 + mh;
    #pragma unroll
    for (int i = 0; i < 32; i += 8)
      *(s16x8_t*)(dst + i) = *(const s16x8_t*)(Tb + e*72 + mh + i);
  }
}

// ---------------------------------------------------------------------------
// Main: out[b][n][e] = dinv[n]*( sum_m bf16(A[n][m])*bf16(h[m][e]) + (1-bf16(diag))*h[n][e] )
//   dinv[n] = 1/(rowsum_f32(A)[n] - diag[n] + 1)
// Barrier-free K-loop: B-fragments read directly from L2-resident hT.
// 512 blocks (2/CU), 4 waves: wave pair (khalf) splits K; one LDS reduction at end.
// b = bid&7 keeps each XCD's L2 on a single hT[b] (512 KB).
// ---------------------------------------------------------------------------
#define LOADA(d0_,d1_,d2_,d3_, tt) do {                 \
    const float* _ap = Arow + k0 + (tt)*64 + kc*8;      \
    d0_ = *(const float4*)(_ap);                        \
    d1_ = *(const float4*)(_ap+4);                      \
    d2_ = *(const float4*)(_ap+32);                     \
    d3_ = *(const float4*)(_ap+36);                     \
  } while(0)

__global__ __launch_bounds__(256, 2) void gc_main(const float* __restrict__ A,
                                                  const unsigned short* __restrict__ h,
                                                  const unsigned short* __restrict__ hT,
                                                  float* __restrict__ out){
  __shared__ float red[2][16*128];     // K-high partial C (per row-pair)
  __shared__ float rsred[2][16];       // K-high partial rowsums

  const int tid = threadIdx.x;
  const int w = tid >> 6, l = tid & 63;
  const int bid = blockIdx.x;          // 0..511
  const int b  = bid & 7;              // XCD-affine
  const int xt = bid >> 3;             // 0..63
  const int wpair = w & 1;             // which 16-row group
  const int khalf = w >> 1;            // 0: K in [0,1024), 1: [1024,2048)
  const int wm0 = xt*32 + wpair*16;
  const int rl = l & 15, kc = l >> 4;
  const int myrow = wm0 + rl;
  const int k0 = khalf * 1024;

  const float* Arow = A + ((size_t)(b*NN + myrow))*NN;
  const unsigned short* hTb = hT + (size_t)b * DD * NN;

  // diag needed only by epilogue waves; load early to hide latency
  const float diagv = (khalf == 0) ? Arow[myrow] : 0.f;

  // B row pointers: lane holds hT[col = n*16+rl][k-chunk kc*8]
  const unsigned short* Bp[8];
  #pragma unroll
  for (int n=0;n<8;n++) Bp[n] = hTb + (size_t)(n*16 + rl)*NN + k0 + kc*8;

  f32x4_t acc[8];
  #pragma unroll
  for (int n=0;n<8;n++) acc[n] = (f32x4_t){0.f,0.f,0.f,0.f};
  float rsum = 0.f;

  float4 a0,a1,a2,a3, b0,b1,b2,b3, p0,p1,p2,p3;
  LOADA(a0,a1,a2,a3, 0);
  LOADA(b0,b1,b2,b3, 1);
  s16x8_t B0[8];
  #pragma unroll
  for (int n=0;n<8;n++) B0[n] = *(const s16x8_t*)(Bp[n]);

  for (int t = 0; t < 16; t++){
    const int tp = (t+2 < 16) ? t+2 : 15;
    const int tn = (t+1 < 16) ? t+1 : 15;
    LOADA(p0,p1,p2,p3, tp);                       // A prefetch, distance 2
    s16x8_t B1[8];
    #pragma unroll
    for (int n=0;n<8;n++) B1[n] = *(const s16x8_t*)(Bp[n] + t*64 + 32);   // kk=1
    // kk = 0
    {
      float s0 = (a0.x+a0.y)+(a0.z+a0.w);
      float s1 = (a1.x+a1.y)+(a1.z+a1.w);
      rsum += s0+s1;
      s16x8_t af = pack_bf16_8(a0,a1);
      #pragma unroll
      for (int n=0;n<8;n++)
        acc[n] = __builtin_amdgcn_mfma_f32_16x16x32_bf16(af, B0[n], acc[n], 0,0,0);
    }
    #pragma unroll
    for (int n=0;n<8;n++) B0[n] = *(const s16x8_t*)(Bp[n] + tn*64);       // next kk=0
    // kk = 1
    {
      float s0 = (a2.x+a2.y)+(a2.z+a2.w);
      float s1 = (a3.x+a3.y)+(a3.z+a3.w);
      rsum += s0+s1;
      s16x8_t af = pack_bf16_8(a2,a3);
      #pragma unroll
      for (int n=0;n<8;n++)
        acc[n] = __builtin_amdgcn_mfma_f32_16x16x32_bf16(af, B1[n], acc[n], 0,0,0);
    }
    a0=b0; a1=b1; a2=b2; a3=b3;
    b0=p0; b1=p1; b2=p2; b3=p3;
  }

  // per-row K-half rowsum (lanes l, l^16, l^32, l^48 share a row)
  rsum += __shfl_xor(rsum, 16);
  rsum += __shfl_xor(rsum, 32);

  if (khalf == 1){
    float* rb_ = &red[wpair][0];
    #pragma unroll
    for (int n=0;n<8;n++)
      #pragma unroll
      for (int j=0;j<4;j++)
        rb_[(kc*4+j)*128 + n*16 + rl] = acc[n][j];
    if (l < 16) rsred[wpair][l] = rsum;
  }
  __syncthreads();
  if (khalf == 0){
    const float rall = rsum + rsred[wpair][rl];
    const float dinv = 1.0f / (rall - diagv + 1.0f);
    const float dfac = 1.0f - bf2f(f2bf(diagv));  // undo exactly what MFMA added
    const float* rb_ = &red[wpair][0];
    const unsigned short* hb_ = h + (size_t)b * NN * DD;
    float* outb = out + (size_t)b * NN * DD;
    #pragma unroll
    for (int j = 0; j < 4; j++){
      const int row_l = kc*4 + j;                 // C/D: row = (l>>4)*4 + reg
      const int rowg = wm0 + row_l;
      const float dj = __shfl(dinv, row_l);
      const float fj = __shfl(dfac, row_l);
      #pragma unroll
      for (int n = 0; n < 8; n++){
        const int col = n*16 + rl;                // C/D: col = l&15
        const float part = acc[n][j] + rb_[row_l*128 + col];
        const float hv = bf2f(hb_[(size_t)rowg*DD + col]);
        outb[(size_t)rowg*DD + col] = dj * (part + fj * hv);
      }
    }
  }
}

extern "C" void kernel_launch(void* const* d_in, const int* in_sizes, int n_in,
                              void* d_out, int out_size, void* d_ws, size_t ws_size,
                              hipStream_t stream){
  const float* x = (const float*)d_in[0];
  const float* A = (const float*)d_in[1];
  const float* W = (const float*)d_in[2];
  float* out = (float*)d_out;

  unsigned short* h  = (unsigned short*)d_ws;                       // 4 MB
  unsigned short* hT = h + (size_t)BB*NN*DD;                        // 4 MB

  gc_phase1<<<dim3(256), dim3(256), 0, stream>>>(x, W, h, hT);
  gc_main  <<<dim3(512), dim3(256), 0, stream>>>(A, h, hT, out);
}

// Round 4
// 265.084 us; speedup vs baseline: 1.0024x; 1.0024x over previous
//
#include <hip/hip_runtime.h>
#include <hip/hip_bf16.h>

#define BB 8
#define NN 2048
#define DD 128

typedef float f32x4_t __attribute__((ext_vector_type(4)));
typedef short s16x8_t __attribute__((ext_vector_type(8)));

__device__ __forceinline__ unsigned short f2bf(float f){
  union { float f; unsigned int u; } v; v.f = f;
  unsigned int u = v.u;
  u += 0x7FFFu + ((u >> 16) & 1u);   // RNE
  return (unsigned short)(u >> 16);
}
__device__ __forceinline__ float bf2f(unsigned short s){
  union { unsigned int u; float f; } v; v.u = ((unsigned int)s) << 16;
  return v.f;
}
__device__ __forceinline__ s16x8_t pack_bf16_8(const float4 lo, const float4 hi){
  union { __hip_bfloat162 p[4]; s16x8_t v; } U;
  U.p[0] = __float22bfloat162_rn(float2{lo.x, lo.y});
  U.p[1] = __float22bfloat162_rn(float2{lo.z, lo.w});
  U.p[2] = __float22bfloat162_rn(float2{hi.x, hi.y});
  U.p[3] = __float22bfloat162_rn(float2{hi.z, hi.w});
  return U.v;
}

// ---------------------------------------------------------------------------
// Phase 1: h[b][m][e] = leaky_relu(sum_d x[b][m][d] * W[e][d]) in bf16,
// plus transposed copy hT[b][e][m].  1D grid of 256, b = bid&7 (XCD-affine).
// (unchanged from round 2 — isolate the gc_main fix)
// ---------------------------------------------------------------------------
__global__ __launch_bounds__(256) void gc_phase1(const float* __restrict__ x,
                                                 const float* __restrict__ W,
                                                 unsigned short* __restrict__ h,
                                                 unsigned short* __restrict__ hT){
  __shared__ float smem[64*132 + 128*128];   // xs[64][132] + WT[128][128]
  float* xs = smem;
  float* WT = smem + 64*132;

  const int t   = threadIdx.x;
  const int bid = blockIdx.x;
  const int b   = bid & 7;
  const int m0  = (bid >> 3) * 64;

  {
    const int e = t >> 1, d0 = (t & 1) * 64;
    const float* wr = W + e*DD + d0;
    #pragma unroll
    for (int i = 0; i < 64; i += 4){
      float4 wv = *(const float4*)(wr + i);
      WT[(d0+i+0)*128 + e] = wv.x;
      WT[(d0+i+1)*128 + e] = wv.y;
      WT[(d0+i+2)*128 + e] = wv.z;
      WT[(d0+i+3)*128 + e] = wv.w;
    }
  }
  #pragma unroll
  for (int i = 0; i < 8; i++){
    int s = t + i*256;
    int row = s >> 5, c4 = (s & 31) * 4;
    float4 xv = *(const float4*)(x + ((size_t)(b*NN + m0 + row))*DD + c4);
    *(float4*)(xs + row*132 + c4) = xv;
  }
  __syncthreads();

  const int rg = t >> 4, cg = t & 15;
  const int r0 = rg*4, c0 = cg*8;
  float acc[4][8];
  #pragma unroll
  for (int i=0;i<4;i++)
    #pragma unroll
    for (int j=0;j<8;j++) acc[i][j] = 0.f;

  #pragma unroll 2
  for (int d = 0; d < 128; d += 4){
    float4 xv[4];
    #pragma unroll
    for (int i=0;i<4;i++) xv[i] = *(const float4*)(xs + (r0+i)*132 + d);
    #pragma unroll
    for (int dd=0; dd<4; dd++){
      float4 wa = *(const float4*)(WT + (d+dd)*128 + c0);
      float4 wb = *(const float4*)(WT + (d+dd)*128 + c0 + 4);
      #pragma unroll
      for (int i=0;i<4;i++){
        float xq = (dd==0)?xv[i].x:(dd==1)?xv[i].y:(dd==2)?xv[i].z:xv[i].w;
        acc[i][0] += xq*wa.x; acc[i][1] += xq*wa.y;
        acc[i][2] += xq*wa.z; acc[i][3] += xq*wa.w;
        acc[i][4] += xq*wb.x; acc[i][5] += xq*wb.y;
        acc[i][6] += xq*wb.z; acc[i][7] += xq*wb.w;
      }
    }
  }

  unsigned short hb[4][8];
  #pragma unroll
  for (int i=0;i<4;i++){
    s16x8_t st;
    #pragma unroll
    for (int j=0;j<8;j++){
      float v = acc[i][j];
      v = v > 0.f ? v : 0.01f*v;
      hb[i][j] = f2bf(v);
      st[j] = (short)hb[i][j];
    }
    *(s16x8_t*)(h + ((size_t)(b*NN + m0 + r0 + i))*DD + c0) = st;
  }

  __syncthreads();
  unsigned short* Tb = (unsigned short*)smem;   // [128][72] bf16 transpose buffer
  #pragma unroll
  for (int i=0;i<4;i++)
    #pragma unroll
    for (int j=0;j<8;j++)
      Tb[(c0+j)*72 + (r0+i)] = hb[i][j];
  __syncthreads();

  {
    const int e = t >> 1, mh = (t & 1) * 32;
    unsigned short* dst = hT + ((size_t)(b*DD + e))*NN + m0 + mh;
    #pragma unroll
    for (int i = 0; i < 32; i += 8)
      *(s16x8_t*)(dst + i) = *(const s16x8_t*)(Tb + e*72 + mh + i);
  }
}

// ---------------------------------------------------------------------------
// Main: out[b][n][e] = dinv[n]*( sum_m bf16(A[n][m])*bf16(h[m][e]) + (1-bf16(diag))*h[n][e] )
// kk-granular software pipeline (32 steps of 32-K), issue order per step:
//   [B(s+1), A(s+2)]  → the wait on B(s) never forces a same-step A-prefetch
// (vmcnt completes IN ORDER — loads needed soon must be issued before loads
//  needed later; previous version violated this and stalled ~16K cyc/iter).
// ---------------------------------------------------------------------------
__global__ __launch_bounds__(256, 2) void gc_main(const float* __restrict__ A,
                                                  const unsigned short* __restrict__ h,
                                                  const unsigned short* __restrict__ hT,
                                                  float* __restrict__ out){
  __shared__ float red[2][16*128];     // K-high partial C (per row-pair)
  __shared__ float rsred[2][16];       // K-high partial rowsums

  const int tid = threadIdx.x;
  const int w = tid >> 6, l = tid & 63;
  const int bid = blockIdx.x;          // 0..511
  const int b  = bid & 7;              // XCD-affine
  const int xt = bid >> 3;             // 0..63
  const int wpair = w & 1;             // which 16-row group
  const int khalf = w >> 1;            // 0: K in [0,1024), 1: [1024,2048)
  const int wm0 = xt*32 + wpair*16;
  const int rl = l & 15, kc = l >> 4;
  const int myrow = wm0 + rl;
  const int k0 = khalf * 1024;

  const float* Arow = A + ((size_t)(b*NN + myrow))*NN + k0 + kc*8;
  const unsigned short* hTb = hT + (size_t)b * DD * NN;

  // diag: issued first (oldest in the vmcnt queue → never force-stalls later waits)
  const float diagv = (khalf == 0) ? A[((size_t)(b*NN + myrow))*NN + myrow] : 0.f;

  const unsigned short* Bp[8];
  #pragma unroll
  for (int n=0;n<8;n++) Bp[n] = hTb + (size_t)(n*16 + rl)*NN + k0 + kc*8;

  f32x4_t acc[8];
  #pragma unroll
  for (int n=0;n<8;n++) acc[n] = (f32x4_t){0.f,0.f,0.f,0.f};
  float rsum = 0.f;

  s16x8_t Bcur[8], Bnxt[8];
  float4 a0,a1, b0,b1, c0,c1;

  // prologue: B(0) first, then A(0), A(1)
  #pragma unroll
  for (int n=0;n<8;n++) Bcur[n] = *(const s16x8_t*)(Bp[n]);
  { const float* ap = Arow;      a0 = *(const float4*)ap; a1 = *(const float4*)(ap+4); }
  { const float* ap = Arow + 32; b0 = *(const float4*)ap; b1 = *(const float4*)(ap+4); }

  #pragma unroll 4
  for (int s = 0; s < 32; s++){
    const int sn = (s+1 < 32) ? s+1 : 31;
    const int sp = (s+2 < 32) ? s+2 : 31;
    // issue next B FIRST, then the A two steps out
    #pragma unroll
    for (int n=0;n<8;n++) Bnxt[n] = *(const s16x8_t*)(Bp[n] + sn*32);
    { const float* ap = Arow + sp*32; c0 = *(const float4*)ap; c1 = *(const float4*)(ap+4); }

    // compute with A(s) (issued 2 steps ago) and B(s) (issued last step)
    rsum += (a0.x+a0.y)+(a0.z+a0.w) + (a1.x+a1.y)+(a1.z+a1.w);
    s16x8_t af = pack_bf16_8(a0,a1);
    #pragma unroll
    for (int n=0;n<8;n++)
      acc[n] = __builtin_amdgcn_mfma_f32_16x16x32_bf16(af, Bcur[n], acc[n], 0,0,0);

    // rotate
    a0=b0; a1=b1; b0=c0; b1=c1;
    #pragma unroll
    for (int n=0;n<8;n++) Bcur[n] = Bnxt[n];
  }

  // per-row K-half rowsum (lanes l, l^16, l^32, l^48 share a row)
  rsum += __shfl_xor(rsum, 16);
  rsum += __shfl_xor(rsum, 32);

  if (khalf == 1){
    float* rb_ = &red[wpair][0];
    #pragma unroll
    for (int n=0;n<8;n++)
      #pragma unroll
      for (int j=0;j<4;j++)
        rb_[(kc*4+j)*128 + n*16 + rl] = acc[n][j];
    if (l < 16) rsred[wpair][l] = rsum;
  }
  __syncthreads();
  if (khalf == 0){
    const float rall = rsum + rsred[wpair][rl];
    const float dinv = 1.0f / (rall - diagv + 1.0f);
    const float dfac = 1.0f - bf2f(f2bf(diagv));  // undo exactly what MFMA added
    const float* rb_ = &red[wpair][0];
    const unsigned short* hb_ = h + (size_t)b * NN * DD;
    float* outb = out + (size_t)b * NN * DD;
    #pragma unroll
    for (int j = 0; j < 4; j++){
      const int row_l = kc*4 + j;                 // C/D: row = (l>>4)*4 + reg
      const int rowg = wm0 + row_l;
      const float dj = __shfl(dinv, row_l);
      const float fj = __shfl(dfac, row_l);
      #pragma unroll
      for (int n = 0; n < 8; n++){
        const int col = n*16 + rl;                // C/D: col = l&15
        const float part = acc[n][j] + rb_[row_l*128 + col];
        const float hv = bf2f(hb_[(size_t)rowg*DD + col]);
        outb[(size_t)rowg*DD + col] = dj * (part + fj * hv);
      }
    }
  }
}

extern "C" void kernel_launch(void* const* d_in, const int* in_sizes, int n_in,
                              void* d_out, int out_size, void* d_ws, size_t ws_size,
                              hipStream_t stream){
  const float* x = (const float*)d_in[0];
  const float* A = (const float*)d_in[1];
  const float* W = (const float*)d_in[2];
  float* out = (float*)d_out;

  unsigned short* h  = (unsigned short*)d_ws;                       // 4 MB
  unsigned short* hT = h + (size_t)BB*NN*DD;                        // 4 MB

  gc_phase1<<<dim3(256), dim3(256), 0, stream>>>(x, W, h, hT);
  gc_main  <<<dim3(512), dim3(256), 0, stream>>>(A, h, hT, out);
}

// Round 6
// 229.005 us; speedup vs baseline: 1.1603x; 1.1575x over previous
//
#include <hip/hip_runtime.h>
#include <hip/hip_bf16.h>

#define BB 8
#define NN 2048
#define DD 128

typedef float f32x4_t __attribute__((ext_vector_type(4)));
typedef short s16x8_t __attribute__((ext_vector_type(8)));
typedef short s16x4_t __attribute__((ext_vector_type(4)));

__device__ __forceinline__ unsigned short f2bf(float f){
  union { float f; unsigned int u; } v; v.f = f;
  unsigned int u = v.u;
  u += 0x7FFFu + ((u >> 16) & 1u);   // RNE
  return (unsigned short)(u >> 16);
}
__device__ __forceinline__ float bf2f(unsigned short s){
  union { unsigned int u; float f; } v; v.u = ((unsigned int)s) << 16;
  return v.f;
}

// ---------------------------------------------------------------------------
// Phase 1: h[b][m][e] = leaky_relu(sum_d x[b][m][d] * W[e][d]) in bf16,
// plus transposed copy hT[b][e][m].  (unchanged — isolate gc_main changes)
// ---------------------------------------------------------------------------
__global__ __launch_bounds__(256) void gc_phase1(const float* __restrict__ x,
                                                 const float* __restrict__ W,
                                                 unsigned short* __restrict__ h,
                                                 unsigned short* __restrict__ hT){
  __shared__ float smem[64*132 + 128*128];   // xs[64][132] + WT[128][128]
  float* xs = smem;
  float* WT = smem + 64*132;

  const int t   = threadIdx.x;
  const int bid = blockIdx.x;
  const int b   = bid & 7;
  const int m0  = (bid >> 3) * 64;

  {
    const int e = t >> 1, d0 = (t & 1) * 64;
    const float* wr = W + e*DD + d0;
    #pragma unroll
    for (int i = 0; i < 64; i += 4){
      float4 wv = *(const float4*)(wr + i);
      WT[(d0+i+0)*128 + e] = wv.x;
      WT[(d0+i+1)*128 + e] = wv.y;
      WT[(d0+i+2)*128 + e] = wv.z;
      WT[(d0+i+3)*128 + e] = wv.w;
    }
  }
  #pragma unroll
  for (int i = 0; i < 8; i++){
    int s = t + i*256;
    int row = s >> 5, c4 = (s & 31) * 4;
    float4 xv = *(const float4*)(x + ((size_t)(b*NN + m0 + row))*DD + c4);
    *(float4*)(xs + row*132 + c4) = xv;
  }
  __syncthreads();

  const int rg = t >> 4, cg = t & 15;
  const int r0 = rg*4, c0 = cg*8;
  float acc[4][8];
  #pragma unroll
  for (int i=0;i<4;i++)
    #pragma unroll
    for (int j=0;j<8;j++) acc[i][j] = 0.f;

  #pragma unroll 2
  for (int d = 0; d < 128; d += 4){
    float4 xv[4];
    #pragma unroll
    for (int i=0;i<4;i++) xv[i] = *(const float4*)(xs + (r0+i)*132 + d);
    #pragma unroll
    for (int dd=0; dd<4; dd++){
      float4 wa = *(const float4*)(WT + (d+dd)*128 + c0);
      float4 wb = *(const float4*)(WT + (d+dd)*128 + c0 + 4);
      #pragma unroll
      for (int i=0;i<4;i++){
        float xq = (dd==0)?xv[i].x:(dd==1)?xv[i].y:(dd==2)?xv[i].z:xv[i].w;
        acc[i][0] += xq*wa.x; acc[i][1] += xq*wa.y;
        acc[i][2] += xq*wa.z; acc[i][3] += xq*wa.w;
        acc[i][4] += xq*wb.x; acc[i][5] += xq*wb.y;
        acc[i][6] += xq*wb.z; acc[i][7] += xq*wb.w;
      }
    }
  }

  unsigned short hb[4][8];
  #pragma unroll
  for (int i=0;i<4;i++){
    s16x8_t st;
    #pragma unroll
    for (int j=0;j<8;j++){
      float v = acc[i][j];
      v = v > 0.f ? v : 0.01f*v;
      hb[i][j] = f2bf(v);
      st[j] = (short)hb[i][j];
    }
    *(s16x8_t*)(h + ((size_t)(b*NN + m0 + r0 + i))*DD + c0) = st;
  }

  __syncthreads();
  unsigned short* Tb = (unsigned short*)smem;   // [128][72] bf16 transpose buffer
  #pragma unroll
  for (int i=0;i<4;i++)
    #pragma unroll
    for (int j=0;j<8;j++)
      Tb[(c0+j)*72 + (r0+i)] = hb[i][j];
  __syncthreads();

  {
    const int e = t >> 1, mh = (t & 1) * 32;
    unsigned short* dst = hT + ((size_t)(b*DD + e))*NN + m0 + mh;
    #pragma unroll
    for (int i = 0; i < 32; i += 8)
      *(s16x8_t*)(dst + i) = *(const s16x8_t*)(Tb + e*72 + mh + i);
  }
}

// ---------------------------------------------------------------------------
// Main GEMM (K-split 2): Cpart[kh][b][m][e] = sum_{k in half} bf16A * bf16h,
// RSpart[kh][b][m] = f32 rowsum of A over the half.
// 512 blocks (2/CU), 256 thr. BM=64, BK=64, LDS-staged both operands:
//   A: reg-staged f32->bf16, coalesced 256B row segs, XOR-swizzled ds_write
//   B: global_load_lds(16B) from hT, pre-swizzled source (LDS[e][c]=glob[e][c^(e&7)])
// Single barrier per K-step (writes go to the buffer read 2 steps ago).
// ---------------------------------------------------------------------------
__global__ __launch_bounds__(256, 2) void gc_main(const float* __restrict__ A,
                                                  const unsigned short* __restrict__ hT,
                                                  float* __restrict__ Cpart,
                                                  float* __restrict__ RSpart){
  __shared__ unsigned short Asw[2][64*64];     // 8 KB each, chunk c' = c ^ (row&7)
  __shared__ unsigned short Bsw[2][128*64];    // 16 KB each, chunk c' = c ^ (e&7)

  const int tid = threadIdx.x;
  const int w = tid >> 6, l = tid & 63;
  const int bid = blockIdx.x;
  const int b    = bid & 7;                    // XCD-affine
  const int rest = bid >> 3;
  const int kh   = rest & 1;
  const int m0   = (rest >> 1) * 64;
  const int k0   = kh * 1024;

  const int rl = l & 15, kc = l >> 4;

  const float* Ab = A + (size_t)b*NN*NN;
  const unsigned short* hTb = hT + (size_t)b*DD*NN;

  // ---- B staging (global_load_lds, pre-swizzled source)
  const int e_base = w*32 + (l>>3);
  const int csw    = (l&7) ^ ((l>>3)&7);
  const unsigned short* bsrc0 = hTb + (size_t)e_base*NN + k0 + csw*8;

  auto stageB = [&](int bi, int t){
    #pragma unroll
    for (int q = 0; q < 4; q++){
      const unsigned short* src = bsrc0 + (size_t)q*8*NN + t*64;
      unsigned short* dst = &Bsw[bi][(w*32 + q*8)*64];
      __builtin_amdgcn_global_load_lds((const __attribute__((address_space(1))) void*)src,
                                       (__attribute__((address_space(3))) void*)dst,
                                       16, 0, 0);
    }
  };

  // ---- A reg staging (coalesced f32)
  const int ar_ = tid >> 4;            // base row 0..15 (thread owns rows ar_+16i)
  const int ac_ = tid & 15;            // 16B window within 256B row segment
  const float* asrc0 = Ab + (size_t)(m0 + ar_)*NN + k0 + ac_*4;

  float4 av[4];
  auto loadA = [&](int t){
    #pragma unroll
    for (int i = 0; i < 4; i++)
      av[i] = *(const float4*)(asrc0 + (size_t)(16*i)*NN + t*64);
  };

  float rs[4] = {0.f,0.f,0.f,0.f};
  const int cw = ac_ >> 1, sub = ac_ & 1;
  auto writeA = [&](int bi){
    #pragma unroll
    for (int i = 0; i < 4; i++){
      rs[i] += (av[i].x+av[i].y)+(av[i].z+av[i].w);
      const int r = ar_ + 16*i;
      union { __hip_bfloat162 p[2]; s16x4_t v; } U;
      U.p[0] = __float22bfloat162_rn(float2{av[i].x, av[i].y});
      U.p[1] = __float22bfloat162_rn(float2{av[i].z, av[i].w});
      *(s16x4_t*)&Asw[bi][r*64 + ((cw ^ (r&7))<<3) + sub*4] = U.v;
    }
  };

  f32x4_t acc[8];
  #pragma unroll
  for (int n=0;n<8;n++) acc[n] = (f32x4_t){0.f,0.f,0.f,0.f};

  // prologue
  stageB(0, 0);
  loadA(0);
  writeA(0);
  __syncthreads();     // drains gload_lds B0 + makes A0 writes visible

  const int arow = w*16 + rl;
  for (int t = 0; t < 16; t++){
    const int cur = t & 1, nx = cur ^ 1;
    if (t < 15){ stageB(nx, t+1); loadA(t+1); }
    #pragma unroll
    for (int kk = 0; kk < 2; kk++){
      const s16x8_t afrag = *(const s16x8_t*)&Asw[cur][arow*64 + (((kk*4+kc) ^ (rl&7))<<3)];
      #pragma unroll
      for (int n = 0; n < 8; n++){
        const int e = n*16 + rl;
        const s16x8_t bfrag = *(const s16x8_t*)&Bsw[cur][e*64 + (((kk*4+kc) ^ (rl&7))<<3)];
        acc[n] = __builtin_amdgcn_mfma_f32_16x16x32_bf16(afrag, bfrag, acc[n], 0,0,0);
      }
    }
    if (t < 15) writeA(nx);
    __syncthreads();   // one barrier/step: writes target buffer read 2 steps ago
  }

  // rowsum: reduce across the 16 threads sharing each row set (same tid>>4)
  #pragma unroll
  for (int i=0;i<4;i++){
    rs[i] += __shfl_xor(rs[i], 1);
    rs[i] += __shfl_xor(rs[i], 2);
    rs[i] += __shfl_xor(rs[i], 4);
    rs[i] += __shfl_xor(rs[i], 8);
  }
  if ((l & 15) == 0){
    #pragma unroll
    for (int i=0;i<4;i++)
      RSpart[((size_t)kh*BB + b)*NN + m0 + ar_ + 16*i] = rs[i];
  }

  // partial C write (f32)
  float* Cp = Cpart + (((size_t)kh*BB + b)*NN + m0)*DD;
  #pragma unroll
  for (int j = 0; j < 4; j++){
    const int row_l = w*16 + kc*4 + j;       // C/D: row=(l>>4)*4+reg, col=l&15
    #pragma unroll
    for (int n = 0; n < 8; n++)
      Cp[(size_t)row_l*DD + n*16 + rl] = acc[n][j];
  }
}

// ---------------------------------------------------------------------------
// Reduce: out[b][n][e] = dinv*(C0+C1 + (1-bf16(diag))*h[n][e])
//   dinv = 1/(rs0+rs1 - diag + 1)
// ---------------------------------------------------------------------------
__global__ __launch_bounds__(256) void gc_reduce(const float* __restrict__ A,
                                                 const unsigned short* __restrict__ h,
                                                 const float* __restrict__ Cpart,
                                                 const float* __restrict__ RSpart,
                                                 float* __restrict__ out){
  const int tid = threadIdx.x;
  const int bid = blockIdx.x;          // 1024 blocks: b = bid&7, 16 rows each
  const int b   = bid & 7;
  const int row = (bid >> 3)*16 + (tid >> 4);
  const int e0  = (tid & 15) * 8;

  const float rsum = RSpart[(size_t)b*NN + row] + RSpart[((size_t)BB + b)*NN + row];
  const float diag = A[((size_t)b*NN + row)*NN + row];
  const float dinv = 1.0f / (rsum - diag + 1.0f);
  const float dfac = 1.0f - bf2f(f2bf(diag));

  const size_t off = ((size_t)b*NN + row)*DD + e0;
  const float* c0 = Cpart + ((size_t)b*NN + row)*DD + e0;
  const float* c1 = Cpart + (((size_t)BB + b)*NN + row)*DD + e0;
  float4 p0a = *(const float4*)(c0),   p0b = *(const float4*)(c0+4);
  float4 p1a = *(const float4*)(c1),   p1b = *(const float4*)(c1+4);
  s16x8_t hv = *(const s16x8_t*)(h + off);

  float4 oa, ob;
  oa.x = dinv*(p0a.x + p1a.x + dfac*bf2f((unsigned short)hv[0]));
  oa.y = dinv*(p0a.y + p1a.y + dfac*bf2f((unsigned short)hv[1]));
  oa.z = dinv*(p0a.z + p1a.z + dfac*bf2f((unsigned short)hv[2]));
  oa.w = dinv*(p0a.w + p1a.w + dfac*bf2f((unsigned short)hv[3]));
  ob.x = dinv*(p0b.x + p1b.x + dfac*bf2f((unsigned short)hv[4]));
  ob.y = dinv*(p0b.y + p1b.y + dfac*bf2f((unsigned short)hv[5]));
  ob.z = dinv*(p0b.z + p1b.z + dfac*bf2f((unsigned short)hv[6]));
  ob.w = dinv*(p0b.w + p1b.w + dfac*bf2f((unsigned short)hv[7]));

  *(float4*)(out + off)     = oa;
  *(float4*)(out + off + 4) = ob;
}

extern "C" void kernel_launch(void* const* d_in, const int* in_sizes, int n_in,
                              void* d_out, int out_size, void* d_ws, size_t ws_size,
                              hipStream_t stream){
  const float* x = (const float*)d_in[0];
  const float* A = (const float*)d_in[1];
  const float* W = (const float*)d_in[2];
  float* out = (float*)d_out;

  unsigned short* h  = (unsigned short*)d_ws;                        // 4 MB
  unsigned short* hT = h + (size_t)BB*NN*DD;                         // 4 MB
  float* Cpart  = (float*)((char*)d_ws + (size_t)16*1024*1024);      // 16 MB (2 halves)
  float* RSpart = (float*)((char*)d_ws + (size_t)33*1024*1024);      // 128 KB

  gc_phase1<<<dim3(256),  dim3(256), 0, stream>>>(x, W, h, hT);
  gc_main  <<<dim3(512),  dim3(256), 0, stream>>>(A, hT, Cpart, RSpart);
  gc_reduce<<<dim3(1024), dim3(256), 0, stream>>>(A, h, Cpart, RSpart, out);
}